// Round 9
// baseline (212.691 us; speedup 1.0000x reference)
//
#include <hip/hip_runtime.h>
#include <hip/hip_bf16.h>

#define FEATSZ 2048
#define HIDSZ  1024
#define ATTSZ  512
#define BATCH  64
#define FEATN  512

typedef float  f32x4  __attribute__((ext_vector_type(4)));
typedef __bf16 bf16x8 __attribute__((ext_vector_type(8)));

__device__ __forceinline__ unsigned short f2bf(float f) {
    union { float f; unsigned int u; } x; x.f = f;
    unsigned int u = x.u;
    return (unsigned short)((u + 0x7fffu + ((u >> 16) & 1u)) >> 16);
}

// ---------------- K0a: h = key @ wh_w.T + wh_b  (64 x 512) ----------------
__global__ void k_h(const float* __restrict__ key, const float* __restrict__ wh_w,
                    const float* __restrict__ wh_b, float* __restrict__ h) {
    const int b = blockIdx.y;
    const int ac = blockIdx.x;
    const int t = threadIdx.x;         // 256
    const int lane = t & 63, wv = t >> 6;
    float k16[16];
    const float* kb = key + b * HIDSZ;
#pragma unroll
    for (int j = 0; j < 16; ++j) k16[j] = kb[lane + 64 * j];
#pragma unroll 1
    for (int i = 0; i < 16; ++i) {
        int a = ac * 64 + wv * 16 + i;
        const float* wr = wh_w + (size_t)a * HIDSZ;
        float s = 0.f;
#pragma unroll
        for (int j = 0; j < 16; ++j) s += k16[j] * wr[lane + 64 * j];
#pragma unroll
        for (int d = 32; d; d >>= 1) s += __shfl_xor(s, d);
        if (lane == 0) h[b * ATTSZ + a] = s + wh_b[a];
    }
}

// ------- K0b: convert wv_w (512x2048 f32) -> bf16 in MFMA-fragment order -------
// frag (kk, CF) = 1024B at (kk*32+CF)*1024; lane l holds 16B (8 bf16) at +l*16.
__global__ void k_wvcvt(const float* __restrict__ wv_w, unsigned short* __restrict__ wvb) {
    int idx = blockIdx.x * 256 + threadIdx.x;       // < 512*2048
    int a = idx >> 11, k = idx & 2047;
    int CF = a >> 4, c = a & 15, ks = k >> 5, kin = k & 31;
    int lane = c + ((kin >> 3) << 4);
    int dst = ((ks * 32 + CF) * 64 + lane) * 8 + (kin & 7);
    wvb[dst] = f2bf(wv_w[idx]);
}

// ---------------- K1: fused GEMM(feats, wv^T) + tanh·wa -> partial scores -------
// Economy 2-phase: 1024 blocks (2/CU resident), 512 thr (8 waves, 2x4 grid).
// Block = 64 rows x 256 cols (ncol = bx&1); wave = 32 rows x 64 cols, acc=32 VGPR.
// BK=64, 32 kiters. A bf16 in LDS stride-144 + chunk-XOR (conflict-free reads);
// A reg-staged (T14: B-loads issued BEFORE A-globals so MFMA never waits on HBM;
// A-global wait lands only at post-barrier ds_write, one kiter of cover).
__global__ __launch_bounds__(512) void k_scores(
        const float* __restrict__ feats, const unsigned short* __restrict__ wvb,
        const float* __restrict__ h, const float* __restrict__ wv_b,
        const float* __restrict__ wa, float* __restrict__ part_sc) {
    __shared__ __align__(16) char Alds[2][64 * 144];   // 9216 B per buf
    __shared__ float scp[4][64];
    const int t = threadIdx.x, lane = t & 63, w = t >> 6;
    const int wr = w >> 2, wc = w & 3;
    const int mb = blockIdx.x >> 1, ncol = blockIdx.x & 1;
    const int m0 = mb * 64;
    const int b = mb >> 3;                          // batch = m0/512

    // ---- staging map: thread -> row = t>>3, phys chunk cs = t&7; logical = cs^(row&7)
    const int srow = t >> 3, scs = t & 7;
    const float* gsrc = feats + (size_t)(m0 + srow) * FEATSZ + ((scs ^ (srow & 7)) * 8);
    const int swb = srow * 144 + scs * 16;          // LDS byte offset (within buf)

    // ---- B frags: CF = ncol*16 + wc*4 + cf; frag kk at (kk*32+CF)*512 shorts
    const unsigned short* wb = wvb + (size_t)(ncol * 16 + wc * 4) * 512 + lane * 8;

    // ---- A frag read addrs: row = wr*32 + m*16 + (lane&15); logical chunk ks*4+q,
    //      phys = logical ^ (row&7) (row&7 == lane&7). addr = row*144 + phys*16.
    const int q = lane >> 4, x = lane & 7;
    const int abase0 = (wr * 32 + (lane & 15)) * 144;
    const int abase1 = (wr * 32 + 16 + (lane & 15)) * 144;
    const int cidx0 = ((q)     ^ x) * 16;           // ks=0
    const int cidx1 = ((4 + q) ^ x) * 16;           // ks=1

    f32x4 acc[2][4];
#pragma unroll
    for (int m = 0; m < 2; ++m)
#pragma unroll
        for (int cf = 0; cf < 4; ++cf) acc[m][cf] = (f32x4)0.0f;

    // ---- prologue: stage kiter 0 into buf0
    {
        f32x4 u0 = *(const f32x4*)(gsrc);
        f32x4 u1 = *(const f32x4*)(gsrc + 4);
        bf16x8 v;
        v[0] = (__bf16)u0[0]; v[1] = (__bf16)u0[1]; v[2] = (__bf16)u0[2]; v[3] = (__bf16)u0[3];
        v[4] = (__bf16)u1[0]; v[5] = (__bf16)u1[1]; v[6] = (__bf16)u1[2]; v[7] = (__bf16)u1[3];
        *(bf16x8*)__builtin_assume_aligned(&Alds[0][0] + swb, 16) = v;
        asm volatile("s_waitcnt lgkmcnt(0)" ::: "memory");
        __builtin_amdgcn_s_barrier();
    }

#pragma unroll 2
    for (int j = 0; j < 32; ++j) {
        const char* rbuf = &Alds[j & 1][0];
        char*       wbuf = &Alds[(j & 1) ^ 1][0];
        // B loads for THIS kiter (issued first: MFMA's FIFO wait never touches HBM u's)
        bf16x8 B0[4], B1[4];
#pragma unroll
        for (int cf = 0; cf < 4; ++cf)
            B0[cf] = *(const bf16x8*)(wb + (size_t)((j * 2) * 32 + cf) * 512);
#pragma unroll
        for (int cf = 0; cf < 4; ++cf)
            B1[cf] = *(const bf16x8*)(wb + (size_t)((j * 2 + 1) * 32 + cf) * 512);
        // A-global loads for kiter j+1 (HBM; consumed only at post-barrier write)
        f32x4 u0, u1;
        if (j < 31) {
            u0 = *(const f32x4*)(gsrc + (j + 1) * 64);
            u1 = *(const f32x4*)(gsrc + (j + 1) * 64 + 4);
        }
        // A frags from LDS (conflict-free), then MFMA cluster
        bf16x8 a00 = *(const bf16x8*)__builtin_assume_aligned(rbuf + abase0 + cidx0, 16);
        bf16x8 a01 = *(const bf16x8*)__builtin_assume_aligned(rbuf + abase1 + cidx0, 16);
        bf16x8 a10 = *(const bf16x8*)__builtin_assume_aligned(rbuf + abase0 + cidx1, 16);
        bf16x8 a11 = *(const bf16x8*)__builtin_assume_aligned(rbuf + abase1 + cidx1, 16);
        __builtin_amdgcn_s_setprio(1);
#pragma unroll
        for (int cf = 0; cf < 4; ++cf) acc[0][cf] = __builtin_amdgcn_mfma_f32_16x16x32_bf16(a00, B0[cf], acc[0][cf], 0, 0, 0);
#pragma unroll
        for (int cf = 0; cf < 4; ++cf) acc[1][cf] = __builtin_amdgcn_mfma_f32_16x16x32_bf16(a01, B0[cf], acc[1][cf], 0, 0, 0);
#pragma unroll
        for (int cf = 0; cf < 4; ++cf) acc[0][cf] = __builtin_amdgcn_mfma_f32_16x16x32_bf16(a10, B1[cf], acc[0][cf], 0, 0, 0);
#pragma unroll
        for (int cf = 0; cf < 4; ++cf) acc[1][cf] = __builtin_amdgcn_mfma_f32_16x16x32_bf16(a11, B1[cf], acc[1][cf], 0, 0, 0);
        __builtin_amdgcn_s_setprio(0);
        // b1: all waves done reading wbuf (its last read was kiter j-1)
        __builtin_amdgcn_s_barrier();
        if (j < 31) {
            bf16x8 v;
            v[0] = (__bf16)u0[0]; v[1] = (__bf16)u0[1]; v[2] = (__bf16)u0[2]; v[3] = (__bf16)u0[3];
            v[4] = (__bf16)u1[0]; v[5] = (__bf16)u1[1]; v[6] = (__bf16)u1[2]; v[7] = (__bf16)u1[3];
            *(bf16x8*)__builtin_assume_aligned(wbuf + swb, 16) = v;
        }
        asm volatile("s_waitcnt lgkmcnt(0)" ::: "memory");
        __builtin_amdgcn_s_barrier();   // b2: writes visible before next kiter's reads
    }

    // ---- epilogue: partial score over this block's 256 cols
    const int c16 = lane & 15, q4 = lane >> 4;
    float hreg[4], wreg[4];
#pragma unroll
    for (int cf = 0; cf < 4; ++cf) {
        int a = ncol * 256 + wc * 64 + cf * 16 + c16;
        hreg[cf] = h[b * ATTSZ + a] + wv_b[a];
        wreg[cf] = wa[a];
    }
    float pv[2][4];
#pragma unroll
    for (int m = 0; m < 2; ++m)
#pragma unroll
        for (int jj = 0; jj < 4; ++jj) pv[m][jj] = 0.f;
#pragma unroll
    for (int m = 0; m < 2; ++m)
#pragma unroll
        for (int cf = 0; cf < 4; ++cf)
#pragma unroll
            for (int jj = 0; jj < 4; ++jj)
                pv[m][jj] += tanhf(acc[m][cf][jj] + hreg[cf]) * wreg[cf];
#pragma unroll
    for (int m = 0; m < 2; ++m)
#pragma unroll
        for (int jj = 0; jj < 4; ++jj) {
            float v = pv[m][jj];
            v += __shfl_xor(v, 1); v += __shfl_xor(v, 2);
            v += __shfl_xor(v, 4); v += __shfl_xor(v, 8);
            pv[m][jj] = v;
        }
    if (c16 == 0) {
#pragma unroll
        for (int m = 0; m < 2; ++m)
#pragma unroll
            for (int jj = 0; jj < 4; ++jj)
                scp[wc][wr * 32 + m * 16 + q4 * 4 + jj] = pv[m][jj];
    }
    __syncthreads();
    if (t < 64)
        part_sc[ncol * (BATCH * FEATN) + m0 + t]
            = scp[0][t] + scp[1][t] + scp[2][t] + scp[3][t];
}

// ---------------- K2: softmax over N=512 per batch (sums 2 col-partials) --------
__global__ void k_softmax(const float* __restrict__ part_sc, float* __restrict__ alpha) {
    __shared__ float red[16];
    const int b = blockIdx.x, t = threadIdx.x;     // 512 threads
    const int lane = t & 63, w = t >> 6;
    const int r = b * FEATN + t;
    float s = part_sc[r] + part_sc[BATCH * FEATN + r];
    float m = s;
#pragma unroll
    for (int d = 32; d; d >>= 1) m = fmaxf(m, __shfl_xor(m, d));
    if (lane == 0) red[w] = m;
    __syncthreads();
    if (t == 0) {
        float mm = red[0];
        for (int i = 1; i < 8; ++i) mm = fmaxf(mm, red[i]);
        red[8] = mm;
    }
    __syncthreads();
    float e = __expf(s - red[8]);
    float sum = e;
#pragma unroll
    for (int d = 32; d; d >>= 1) sum += __shfl_xor(sum, d);
    if (lane == 0) red[w] = sum;
    __syncthreads();
    if (t == 0) {
        float ss = 0.f;
        for (int i = 0; i < 8; ++i) ss += red[i];
        red[9] = 1.0f / ss;
    }
    __syncthreads();
    alpha[b * FEATN + t] = e * red[9];
}

// ---------------- K3a: partial att_feats over n-slices ----------------
__global__ void k_att_part(const float* __restrict__ feats, const float* __restrict__ alpha,
                           float* __restrict__ part) {
    const int b = blockIdx.x, fc = blockIdx.y, ns = blockIdx.z, t = threadIdx.x;
    const int f0 = fc * 1024 + t * 4;
    const float* fp = feats + (size_t)(b * FEATN + ns * 128) * FEATSZ + f0;
    const float* al = alpha + b * FEATN + ns * 128;
    float4 acc = {0.f, 0.f, 0.f, 0.f};
#pragma unroll 4
    for (int i = 0; i < 128; ++i) {
        float a = al[i];
        float4 v = *(const float4*)(fp + (size_t)i * FEATSZ);
        acc.x += a * v.x; acc.y += a * v.y; acc.z += a * v.z; acc.w += a * v.w;
    }
    *(float4*)(part + ((size_t)ns * BATCH + b) * FEATSZ + f0) = acc;
}

// ---------------- K3b: reduce 4 partials -> att_feats ----------------
__global__ void k_att_red(const float* __restrict__ part, float* __restrict__ out) {
    const int idx = (blockIdx.x * 256 + threadIdx.x) * 4;   // < 131072
    float4 s = *(const float4*)(part + idx);
#pragma unroll
    for (int z = 1; z < 4; ++z) {
        float4 v = *(const float4*)(part + (size_t)z * (BATCH * FEATSZ) + idx);
        s.x += v.x; s.y += v.y; s.z += v.z; s.w += v.w;
    }
    *(float4*)(out + idx) = s;
}

extern "C" void kernel_launch(void* const* d_in, const int* in_sizes, int n_in,
                              void* d_out, int out_size, void* d_ws, size_t ws_size,
                              hipStream_t stream) {
    const float* feats = (const float*)d_in[0];
    const float* key   = (const float*)d_in[1];
    const float* wh_w  = (const float*)d_in[2];
    const float* wh_b  = (const float*)d_in[3];
    const float* wv_w  = (const float*)d_in[4];
    const float* wv_b  = (const float*)d_in[5];
    const float* wa_w  = (const float*)d_in[6];

    float* out_att   = (float*)d_out;                 // 64*2048
    float* out_alpha = out_att + BATCH * FEATSZ;      // 64*512

    char* ws = (char*)d_ws;
    float* h            = (float*)(ws);               // 128 KB
    float* part_sc      = (float*)(ws + 131072);      // 2 x 128 KB
    unsigned short* wvb = (unsigned short*)(ws + 393216);  // 2 MB
    float* part         = (float*)(ws + 393216);      // 2 MB (reuses wvb after K1)

    hipLaunchKernelGGL(k_h,        dim3(8, 64),    dim3(256), 0, stream, key, wh_w, wh_b, h);
    hipLaunchKernelGGL(k_wvcvt,    dim3(4096),     dim3(256), 0, stream, wv_w, wvb);
    hipLaunchKernelGGL(k_scores,   dim3(1024),     dim3(512), 0, stream, feats, wvb, h, wv_b, wa_w, part_sc);
    hipLaunchKernelGGL(k_softmax,  dim3(64),       dim3(512), 0, stream, part_sc, out_alpha);
    hipLaunchKernelGGL(k_att_part, dim3(64, 2, 4), dim3(256), 0, stream, feats, out_alpha, part);
    hipLaunchKernelGGL(k_att_red,  dim3(128),      dim3(256), 0, stream, part, out_att);
}

// Round 10
// 160.494 us; speedup vs baseline: 1.3252x; 1.3252x over previous
//
#include <hip/hip_runtime.h>
#include <hip/hip_bf16.h>

#define FEATSZ 2048
#define HIDSZ  1024
#define ATTSZ  512
#define BATCH  64
#define FEATN  512

typedef float  f32x4  __attribute__((ext_vector_type(4)));
typedef __bf16 bf16x8 __attribute__((ext_vector_type(8)));

__device__ __forceinline__ unsigned short f2bf(float f) {
    union { float f; unsigned int u; } x; x.f = f;
    unsigned int u = x.u;
    return (unsigned short)((u + 0x7fffu + ((u >> 16) & 1u)) >> 16);
}

// ---------------- K0a: h = key @ wh_w.T + wh_b  (64 x 512) ----------------
__global__ void k_h(const float* __restrict__ key, const float* __restrict__ wh_w,
                    const float* __restrict__ wh_b, float* __restrict__ h) {
    const int b = blockIdx.y;
    const int ac = blockIdx.x;
    const int t = threadIdx.x;         // 256
    const int lane = t & 63, wv = t >> 6;
    float k16[16];
    const float* kb = key + b * HIDSZ;
#pragma unroll
    for (int j = 0; j < 16; ++j) k16[j] = kb[lane + 64 * j];
#pragma unroll 1
    for (int i = 0; i < 16; ++i) {
        int a = ac * 64 + wv * 16 + i;
        const float* wr = wh_w + (size_t)a * HIDSZ;
        float s = 0.f;
#pragma unroll
        for (int j = 0; j < 16; ++j) s += k16[j] * wr[lane + 64 * j];
#pragma unroll
        for (int d = 32; d; d >>= 1) s += __shfl_xor(s, d);
        if (lane == 0) h[b * ATTSZ + a] = s + wh_b[a];
    }
}

// ------- K0b: convert wv_w (512x2048 f32) -> bf16 in MFMA-fragment order -------
// frag (kk, CF) = 1024B at (kk*32+CF)*1024; lane l holds 16B (8 bf16) at +l*16.
__global__ void k_wvcvt(const float* __restrict__ wv_w, unsigned short* __restrict__ wvb) {
    int idx = blockIdx.x * 256 + threadIdx.x;       // < 512*2048
    int a = idx >> 11, k = idx & 2047;
    int CF = a >> 4, c = a & 15, ks = k >> 5, kin = k & 31;
    int lane = c + ((kin >> 3) << 4);
    int dst = ((ks * 32 + CF) * 64 + lane) * 8 + (kin & 7);
    wvb[dst] = f2bf(wv_w[idx]);
}

// ---------------- K1: fused GEMM(feats, wv^T) + tanh·wa -> scores ----------------
// 256 blocks (1/CU), 8 waves. BM=128 x BN=512(full) x BK=32, 64 K-steps.
// A: bf16 in LDS (4 x 8KB bufs), reg-staged 2 steps ahead (glb->cvt->swizzled
// ds_write); cvt happens ONCE per element at stage, not per MFMA use.
// B: L2-resident frag-ordered wvb, 1-step reg ping-pong (named BX/BY).
// ONE lgkmcnt(0)+s_barrier per K-step; NO vmcnt drain anywhere in the loop
// (global->reg waits are wave-private, compiler-tracked, 1-2 steps of cover).
__global__ __launch_bounds__(512) void k_scores(
        const float* __restrict__ feats, const unsigned short* __restrict__ wvb,
        const float* __restrict__ h, const float* __restrict__ wv_b,
        const float* __restrict__ wa, float* __restrict__ scores) {
    __shared__ __align__(16) char Abuf[4][8192];   // [buf][128 rows][32 k] bf16, swizzled
    __shared__ float scp[8][128];
    const int t = threadIdx.x, lane = t & 63, w = t >> 6;
    const int m0 = blockIdx.x * 128, b = blockIdx.x >> 2;

    // ---- staging map: thread t -> row = t>>2, logical 16B chunk sq = t&3 (k = sq*8..)
    // swizzle: phys_chunk = sq ^ ((row>>1)&3)  -> write & read both 2-way max (free)
    const int srow = t >> 2, sq = t & 3;
    const float* gsrc = feats + (size_t)(m0 + srow) * FEATSZ + sq * 8;
    const int wboff = srow * 64 + ((sq ^ ((t >> 3) & 3)) * 16);   // byte offset in buf

    // ---- A frag read addr: frag m: row = m*16+(lane&15), chunk q=lane>>4,
    //      phys = q ^ ((lane>>1)&3)  (row>>1 & 3 == lane>>1 & 3 for bits<4)
    const int rbase = (lane & 15) * 64 + (((lane >> 4) ^ ((lane >> 1) & 3)) * 16);

    // ---- B: wave w covers cols w*64..+64 -> CF = w*4+cf; frag (kk,CF) at +(kk*32+CF)*512
    const unsigned short* wb = wvb + (size_t)(w * 4) * 512 + lane * 8;

    f32x4 acc[8][4];
#pragma unroll
    for (int m = 0; m < 8; ++m)
#pragma unroll
        for (int cf = 0; cf < 4; ++cf) acc[m][cf] = (f32x4)0.0f;

    f32x4 GA0, GA1, GB0, GB1;      // named A-staging regs (even/odd tiles)
    bf16x8 BX[4], BY[4];           // named B ping-pong (even/odd tiles)

    auto loadBX = [&](int tile) {
#pragma unroll
        for (int cf = 0; cf < 4; ++cf) BX[cf] = *(const bf16x8*)(wb + (size_t)(tile * 32 + cf) * 512);
    };
    auto loadBY = [&](int tile) {
#pragma unroll
        for (int cf = 0; cf < 4; ++cf) BY[cf] = *(const bf16x8*)(wb + (size_t)(tile * 32 + cf) * 512);
    };
    auto writeA = [&](f32x4 r0, f32x4 r1, int tile) {
        bf16x8 v;
        v[0] = (__bf16)r0[0]; v[1] = (__bf16)r0[1]; v[2] = (__bf16)r0[2]; v[3] = (__bf16)r0[3];
        v[4] = (__bf16)r1[0]; v[5] = (__bf16)r1[1]; v[6] = (__bf16)r1[2]; v[7] = (__bf16)r1[3];
        *(bf16x8*)__builtin_assume_aligned(&Abuf[tile & 3][0] + wboff, 16) = v;
    };
    auto bar = [&]() {
        asm volatile("s_waitcnt lgkmcnt(0)" ::: "memory");
        __builtin_amdgcn_s_barrier();
        __builtin_amdgcn_sched_barrier(0);
    };

    // ---- prologue: tiles 0,1 in regs; B(0); write tile 0; barrier
    {
        const float* p0 = gsrc;
        GA0 = *(const f32x4*)p0;        GA1 = *(const f32x4*)(p0 + 4);
        const float* p1 = gsrc + 32;
        GB0 = *(const f32x4*)p1;        GB1 = *(const f32x4*)(p1 + 4);
        loadBX(0);
        writeA(GA0, GA1, 0);
        bar();
    }

#pragma unroll 1
    for (int jj = 0; jj < 32; ++jj) {
        const int j = jj * 2;
        // ---- even step j: compute tile j (BX); write tile j+1 (from GB);
        //      issue tile j+2 -> GA; load B(j+1) -> BY
        if (j <= 61) {
            const float* p = gsrc + (j + 2) * 32;
            GA0 = *(const f32x4*)p; GA1 = *(const f32x4*)(p + 4);
        }
        loadBY(j + 1);
        writeA(GB0, GB1, j + 1);
        {
            const char* ab = &Abuf[j & 3][0];
            __builtin_amdgcn_s_setprio(1);
#pragma unroll
            for (int m = 0; m < 8; ++m) {
                bf16x8 a = *(const bf16x8*)__builtin_assume_aligned(ab + m * 1024 + rbase, 16);
#pragma unroll
                for (int cf = 0; cf < 4; ++cf)
                    acc[m][cf] = __builtin_amdgcn_mfma_f32_16x16x32_bf16(a, BX[cf], acc[m][cf], 0, 0, 0);
            }
            __builtin_amdgcn_s_setprio(0);
        }
        bar();
        // ---- odd step j+1: compute tile j+1 (BY); write tile j+2 (from GA);
        //      issue tile j+3 -> GB; load B(j+2) -> BX
        const int j1 = j + 1;
        if (j1 <= 61) {
            const float* p = gsrc + (j1 + 2) * 32;
            GB0 = *(const f32x4*)p; GB1 = *(const f32x4*)(p + 4);
        }
        if (j1 <= 62) loadBX(j1 + 1);
        if (j1 <= 62) writeA(GA0, GA1, j1 + 1);
        {
            const char* ab = &Abuf[j1 & 3][0];
            __builtin_amdgcn_s_setprio(1);
#pragma unroll
            for (int m = 0; m < 8; ++m) {
                bf16x8 a = *(const bf16x8*)__builtin_assume_aligned(ab + m * 1024 + rbase, 16);
#pragma unroll
                for (int cf = 0; cf < 4; ++cf)
                    acc[m][cf] = __builtin_amdgcn_mfma_f32_16x16x32_bf16(a, BY[cf], acc[m][cf], 0, 0, 0);
            }
            __builtin_amdgcn_s_setprio(0);
        }
        bar();
    }

    // ---- epilogue: p[row] = sum_a tanh(acc + h[b,a] + wv_b[a]) * wa[a]
    const int c16 = lane & 15, q4 = lane >> 4;
    float hreg[4], wreg[4];
#pragma unroll
    for (int cf = 0; cf < 4; ++cf) {
        int a = w * 64 + cf * 16 + c16;
        hreg[cf] = h[b * ATTSZ + a] + wv_b[a];
        wreg[cf] = wa[a];
    }
    float pv[8][4];
#pragma unroll
    for (int m = 0; m < 8; ++m)
#pragma unroll
        for (int jr = 0; jr < 4; ++jr) pv[m][jr] = 0.f;
#pragma unroll
    for (int m = 0; m < 8; ++m)
#pragma unroll
        for (int cf = 0; cf < 4; ++cf)
#pragma unroll
            for (int jr = 0; jr < 4; ++jr)
                pv[m][jr] += tanhf(acc[m][cf][jr] + hreg[cf]) * wreg[cf];
#pragma unroll
    for (int m = 0; m < 8; ++m)
#pragma unroll
        for (int jr = 0; jr < 4; ++jr) {
            float v = pv[m][jr];
            v += __shfl_xor(v, 1); v += __shfl_xor(v, 2);
            v += __shfl_xor(v, 4); v += __shfl_xor(v, 8);
            pv[m][jr] = v;
        }
    if (c16 == 0) {
#pragma unroll
        for (int m = 0; m < 8; ++m)
#pragma unroll
            for (int jr = 0; jr < 4; ++jr)
                scp[w][m * 16 + q4 * 4 + jr] = pv[m][jr];
    }
    __syncthreads();
    if (t < 128) {
        float s = 0.f;
#pragma unroll
        for (int ww = 0; ww < 8; ++ww) s += scp[ww][t];
        scores[m0 + t] = s;
    }
}

// ---------------- K2: softmax over N=512 per batch ----------------
__global__ void k_softmax(const float* __restrict__ scores, float* __restrict__ alpha) {
    __shared__ float red[16];
    const int b = blockIdx.x, t = threadIdx.x;     // 512 threads
    const int lane = t & 63, w = t >> 6;
    float s = scores[b * FEATN + t];
    float m = s;
#pragma unroll
    for (int d = 32; d; d >>= 1) m = fmaxf(m, __shfl_xor(m, d));
    if (lane == 0) red[w] = m;
    __syncthreads();
    if (t == 0) {
        float mm = red[0];
        for (int i = 1; i < 8; ++i) mm = fmaxf(mm, red[i]);
        red[8] = mm;
    }
    __syncthreads();
    float e = __expf(s - red[8]);
    float sum = e;
#pragma unroll
    for (int d = 32; d; d >>= 1) sum += __shfl_xor(sum, d);
    if (lane == 0) red[w] = sum;
    __syncthreads();
    if (t == 0) {
        float ss = 0.f;
        for (int i = 0; i < 8; ++i) ss += red[i];
        red[9] = 1.0f / ss;
    }
    __syncthreads();
    alpha[b * FEATN + t] = e * red[9];
}

// ---------------- K3a: partial att_feats over n-slices ----------------
__global__ void k_att_part(const float* __restrict__ feats, const float* __restrict__ alpha,
                           float* __restrict__ part) {
    const int b = blockIdx.x, fc = blockIdx.y, ns = blockIdx.z, t = threadIdx.x;
    const int f0 = fc * 1024 + t * 4;
    const float* fp = feats + (size_t)(b * FEATN + ns * 128) * FEATSZ + f0;
    const float* al = alpha + b * FEATN + ns * 128;
    float4 acc = {0.f, 0.f, 0.f, 0.f};
#pragma unroll 4
    for (int i = 0; i < 128; ++i) {
        float a = al[i];
        float4 v = *(const float4*)(fp + (size_t)i * FEATSZ);
        acc.x += a * v.x; acc.y += a * v.y; acc.z += a * v.z; acc.w += a * v.w;
    }
    *(float4*)(part + ((size_t)ns * BATCH + b) * FEATSZ + f0) = acc;
}

// ---------------- K3b: reduce 4 partials -> att_feats ----------------
__global__ void k_att_red(const float* __restrict__ part, float* __restrict__ out) {
    const int idx = (blockIdx.x * 256 + threadIdx.x) * 4;   // < 131072
    float4 s = *(const float4*)(part + idx);
#pragma unroll
    for (int z = 1; z < 4; ++z) {
        float4 v = *(const float4*)(part + (size_t)z * (BATCH * FEATSZ) + idx);
        s.x += v.x; s.y += v.y; s.z += v.z; s.w += v.w;
    }
    *(float4*)(out + idx) = s;
}

extern "C" void kernel_launch(void* const* d_in, const int* in_sizes, int n_in,
                              void* d_out, int out_size, void* d_ws, size_t ws_size,
                              hipStream_t stream) {
    const float* feats = (const float*)d_in[0];
    const float* key   = (const float*)d_in[1];
    const float* wh_w  = (const float*)d_in[2];
    const float* wh_b  = (const float*)d_in[3];
    const float* wv_w  = (const float*)d_in[4];
    const float* wv_b  = (const float*)d_in[5];
    const float* wa_w  = (const float*)d_in[6];

    float* out_att   = (float*)d_out;                 // 64*2048
    float* out_alpha = out_att + BATCH * FEATSZ;      // 64*512

    char* ws = (char*)d_ws;
    float* h            = (float*)(ws);               // 128 KB
    float* scores       = (float*)(ws + 131072);      // 128 KB
    unsigned short* wvb = (unsigned short*)(ws + 262144);  // 2 MB
    float* part         = (float*)(ws + 262144);      // 2 MB (reuses wvb after K1)

    hipLaunchKernelGGL(k_h,        dim3(8, 64),    dim3(256), 0, stream, key, wh_w, wh_b, h);
    hipLaunchKernelGGL(k_wvcvt,    dim3(4096),     dim3(256), 0, stream, wv_w, wvb);
    hipLaunchKernelGGL(k_scores,   dim3(256),      dim3(512), 0, stream, feats, wvb, h, wv_b, wa_w, scores);
    hipLaunchKernelGGL(k_softmax,  dim3(64),       dim3(512), 0, stream, scores, out_alpha);
    hipLaunchKernelGGL(k_att_part, dim3(64, 2, 4), dim3(256), 0, stream, feats, out_alpha, part);
    hipLaunchKernelGGL(k_att_red,  dim3(128),      dim3(256), 0, stream, part, out_att);
}